// Round 1
// baseline (446.530 us; speedup 1.0000x reference)
//
#include <hip/hip_runtime.h>
#include <math.h>

// Problem constants (from reference):
//   N = 1,000,000 user rows (u_V: N x 64)
//   M =   500,000 item rows (t_V: M x 64, b_V: M x 64)
//   P = N + 2M = 2,000,000 = len(x) = len(w_bias)
//   K = 64, GAMMA = (1,1,1,1)
#define N_U 1000000
#define M_T 500000
#define P_TOT (N_U + 2 * M_T)
#define KDIM 64

// Workspace layout (floats):
//   ws[0]        bias accumulator  (dot(x, w_bias))
//   ws[1]        sum_b_sq accumulator (xb . rownorms(b_V))
//   ws[4]        block-done counter (as unsigned)
//   ws[8..71]    u_vec  (K)
//   ws[72..135]  t_vec  (K)
//   ws[136..199] sum_b  (K)
#define WS_BIAS 0
#define WS_SBSQ 1
#define WS_CTR  4
#define WS_U 8
#define WS_T 72
#define WS_B 136
#define WS_FLOATS 256

// Sparsity-aware accumulate: every accumulated quantity (bias, u_vec, t_vec,
// sum_b, sum_b_sq) is linear in x's entries, so zero entries contribute
// exactly zero — skipping them is exact for any x. The quadratic terms
// (u.t, t.b, b.b, u.b) are formed from the FINAL accumulators in the fused
// last-block epilogue, so exactness is preserved.
//
// Single fused kernel: scan x (float4), gather V-rows at nonzeros (66 in the
// test input), atomically accumulate into ws, then the LAST block to finish
// (device-scope counter) performs the 64-lane shuffle-reduce finalize and
// writes the sigmoid output. Accumulator visibility across blocks:
// __threadfence() before the counter bump on the producer side, agent-scope
// atomic loads (bypass non-coherent per-CU L1) on the consumer side.
__global__ void __launch_bounds__(256) fused_fm_kernel(
    const float* __restrict__ x,
    const float* __restrict__ w_bias,
    const float* __restrict__ u_V,
    const float* __restrict__ t_V,
    const float* __restrict__ b_V,
    const float* __restrict__ w0,
    const float* __restrict__ delta,
    float* __restrict__ ws,
    float* __restrict__ out,
    int P) {
    int gid = blockIdx.x * blockDim.x + threadIdx.x;
    long long base = (long long)gid * 4;

    if (base < P) {  // P % 4 == 0, so base < P implies base+3 < P
        float4 v = *reinterpret_cast<const float4*>(x + base);
        float vals[4] = {v.x, v.y, v.z, v.w};
#pragma unroll
        for (int j = 0; j < 4; ++j) {
            float xv = vals[j];
            if (xv != 0.0f) {
                long long i = base + j;
                // bias term
                atomicAdd(&ws[WS_BIAS], xv * w_bias[i]);
                // pick the V matrix + accumulator for this region of x
                const float* row;
                float* acc;
                bool is_b = false;
                if (i < N_U) {
                    row = u_V + i * KDIM;
                    acc = ws + WS_U;
                } else if (i < (long long)N_U + M_T) {
                    row = t_V + (i - N_U) * KDIM;
                    acc = ws + WS_T;
                } else {
                    row = b_V + (i - N_U - M_T) * KDIM;
                    acc = ws + WS_B;
                    is_b = true;
                }
                float nrm = 0.0f;
                const float4* r4 = reinterpret_cast<const float4*>(row);
#pragma unroll
                for (int k4 = 0; k4 < KDIM / 4; ++k4) {
                    float4 rv = r4[k4];
                    atomicAdd(&acc[k4 * 4 + 0], xv * rv.x);
                    atomicAdd(&acc[k4 * 4 + 1], xv * rv.y);
                    atomicAdd(&acc[k4 * 4 + 2], xv * rv.z);
                    atomicAdd(&acc[k4 * 4 + 3], xv * rv.w);
                    nrm += rv.x * rv.x + rv.y * rv.y + rv.z * rv.z + rv.w * rv.w;
                }
                if (is_b) atomicAdd(&ws[WS_SBSQ], xv * nrm);
            }
        }
    }

    // ---- last-block-done detection (all threads reach here; no early return)
    __shared__ int last;
    __syncthreads();
    if (threadIdx.x == 0) {
        __threadfence();  // make this block's atomics visible before the bump
        unsigned* ctr = reinterpret_cast<unsigned*>(ws) + WS_CTR;
        unsigned old = atomicAdd(ctr, 1u);
        last = (old == gridDim.x - 1) ? 1 : 0;
    }
    __syncthreads();

    if (last && threadIdx.x < 64) {
        __threadfence();
        int k = threadIdx.x;
        float u = __hip_atomic_load(&ws[WS_U + k], __ATOMIC_RELAXED,
                                    __HIP_MEMORY_SCOPE_AGENT);
        float t = __hip_atomic_load(&ws[WS_T + k], __ATOMIC_RELAXED,
                                    __HIP_MEMORY_SCOPE_AGENT);
        float b = __hip_atomic_load(&ws[WS_B + k], __ATOMIC_RELAXED,
                                    __HIP_MEMORY_SCOPE_AGENT);

        float ut = u * t;  // -> dot(u_vec, t_vec)
        float tb = t * b;  // -> dot(t_vec, sum_b)
        float bb = b * b;  // -> dot(sum_b, sum_b)
        float ub = u * b;  // -> dot(u_vec, sum_b)

#pragma unroll
        for (int off = 32; off > 0; off >>= 1) {
            ut += __shfl_down(ut, off);
            tb += __shfl_down(tb, off);
            bb += __shfl_down(bb, off);
            ub += __shfl_down(ub, off);
        }

        if (k == 0) {
            float bias = __hip_atomic_load(&ws[WS_BIAS], __ATOMIC_RELAXED,
                                           __HIP_MEMORY_SCOPE_AGENT);
            float sbsq = __hip_atomic_load(&ws[WS_SBSQ], __ATOMIC_RELAXED,
                                           __HIP_MEMORY_SCOPE_AGENT);
            float bs = 0.5f * (bb - sbsq);
            // GAMMA = (1,1,1,1)
            float y = w0[0] + bias + ut + tb + bs + ub;
            float z = y * delta[0];
            out[0] = 1.0f / (1.0f + expf(-z));
        }
    }
}

extern "C" void kernel_launch(void* const* d_in, const int* in_sizes, int n_in,
                              void* d_out, int out_size, void* d_ws, size_t ws_size,
                              hipStream_t stream) {
    // setup_inputs() order: x, delta, pmi, w_0, w_bias, u_V, t_V, b_V
    const float* x      = (const float*)d_in[0];
    const float* delta  = (const float*)d_in[1];
    // d_in[2] = pmi (unused by reference)
    const float* w0     = (const float*)d_in[3];
    const float* w_bias = (const float*)d_in[4];
    const float* u_V    = (const float*)d_in[5];
    const float* t_V    = (const float*)d_in[6];
    const float* b_V    = (const float*)d_in[7];
    float* out = (float*)d_out;
    float* ws  = (float*)d_ws;

    int P = in_sizes[0];  // 2,000,000

    // Zero accumulators + counter: 1 KB memset instead of a kernel dispatch.
    hipMemsetAsync(ws, 0, WS_FLOATS * sizeof(float), stream);

    int nvec = (P + 3) / 4;              // float4 lanes
    int blocks = (nvec + 255) / 256;     // ~1954 blocks
    hipLaunchKernelGGL(fused_fm_kernel, dim3(blocks), dim3(256), 0, stream,
                       x, w_bias, u_V, t_V, b_V, w0, delta, ws, out, P);
}

// Round 2
// 420.921 us; speedup vs baseline: 1.0608x; 1.0608x over previous
//
#include <hip/hip_runtime.h>
#include <math.h>

// Problem constants (from reference):
//   N = 1,000,000 user rows (u_V: N x 64)
//   M =   500,000 item rows (t_V: M x 64, b_V: M x 64)
//   P = N + 2M = 2,000,000 = len(x) = len(w_bias)
//   K = 64, GAMMA = (1,1,1,1)
#define N_U 1000000
#define M_T 500000
#define P_TOT (N_U + 2 * M_T)
#define KDIM 64

// Workspace layout (floats):
//   ws[0]        bias accumulator  (dot(x, w_bias))
//   ws[1]        sum_b_sq accumulator (xb . rownorms(b_V))
//   ws[8..71]    u_vec  (K)
//   ws[72..135]  t_vec  (K)
//   ws[136..199] sum_b  (K)
#define WS_BIAS 0
#define WS_SBSQ 1
#define WS_U 8
#define WS_T 72
#define WS_B 136
#define WS_FLOATS 256

// NOTE (round-1 post-mortem): a fused single-kernel version with a
// last-block-done counter regressed 422 -> 446 us. The device-scope
// __threadfence() needed in EVERY block before the counter bump is
// expensive on MI355X (8 non-coherent per-XCD L2s -> cross-XCD release
// per block). Separate kernels get cross-block visibility once, at the
// kernel boundary, for free. Keep the 3-dispatch structure.

__global__ void zero_ws_kernel(float* __restrict__ ws) {
    int i = threadIdx.x;
    if (i < WS_FLOATS) ws[i] = 0.0f;
}

// Sparsity-aware accumulate: every term of the FM is linear in x's entries,
// so zero entries contribute exactly zero — skipping them is exact for any x
// with finite weights. Scan x vectorized (float4), gather V-rows only at
// nonzeros (66 in the test input).
__global__ void scan_accum_kernel(const float* __restrict__ x,
                                  const float* __restrict__ w_bias,
                                  const float* __restrict__ u_V,
                                  const float* __restrict__ t_V,
                                  const float* __restrict__ b_V,
                                  float* __restrict__ ws,
                                  int P) {
    int gid = blockIdx.x * blockDim.x + threadIdx.x;
    long long base = (long long)gid * 4;
    if (base >= P) return;

    float4 v = *reinterpret_cast<const float4*>(x + base);
    float vals[4] = {v.x, v.y, v.z, v.w};

#pragma unroll
    for (int j = 0; j < 4; ++j) {
        long long i = base + j;
        if (i >= P) break;
        float xv = vals[j];
        if (xv != 0.0f) {
            // bias term
            atomicAdd(&ws[WS_BIAS], xv * w_bias[i]);
            // pick the V matrix + accumulator for this region of x
            const float* row;
            float* acc;
            bool is_b = false;
            if (i < N_U) {
                row = u_V + i * KDIM;
                acc = ws + WS_U;
            } else if (i < (long long)N_U + M_T) {
                row = t_V + (i - N_U) * KDIM;
                acc = ws + WS_T;
            } else {
                row = b_V + (i - N_U - M_T) * KDIM;
                acc = ws + WS_B;
                is_b = true;
            }
            float nrm = 0.0f;
#pragma unroll
            for (int k = 0; k < KDIM; ++k) {
                float rv = row[k];
                atomicAdd(&acc[k], xv * rv);
                nrm += rv * rv;
            }
            if (is_b) atomicAdd(&ws[WS_SBSQ], xv * nrm);
        }
    }
}

// One wave: four K=64 dot products via shuffle reduction, then sigmoid.
__global__ void finalize_kernel(const float* __restrict__ ws,
                                const float* __restrict__ w0,
                                const float* __restrict__ delta,
                                float* __restrict__ out) {
    int k = threadIdx.x;  // 0..63
    float u = ws[WS_U + k];
    float t = ws[WS_T + k];
    float b = ws[WS_B + k];

    float ut = u * t;  // -> dot(u_vec, t_vec)
    float tb = t * b;  // -> dot(t_vec, sum_b)
    float bb = b * b;  // -> dot(sum_b, sum_b)
    float ub = u * b;  // -> dot(u_vec, sum_b)

#pragma unroll
    for (int off = 32; off > 0; off >>= 1) {
        ut += __shfl_down(ut, off);
        tb += __shfl_down(tb, off);
        bb += __shfl_down(bb, off);
        ub += __shfl_down(ub, off);
    }

    if (k == 0) {
        float bias = ws[WS_BIAS];
        float sbsq = ws[WS_SBSQ];
        float bs = 0.5f * (bb - sbsq);
        // GAMMA = (1,1,1,1)
        float y = w0[0] + bias + ut + tb + bs + ub;
        float z = y * delta[0];
        out[0] = 1.0f / (1.0f + expf(-z));
    }
}

extern "C" void kernel_launch(void* const* d_in, const int* in_sizes, int n_in,
                              void* d_out, int out_size, void* d_ws, size_t ws_size,
                              hipStream_t stream) {
    // setup_inputs() order: x, delta, pmi, w_0, w_bias, u_V, t_V, b_V
    const float* x      = (const float*)d_in[0];
    const float* delta  = (const float*)d_in[1];
    // d_in[2] = pmi (unused by reference)
    const float* w0     = (const float*)d_in[3];
    const float* w_bias = (const float*)d_in[4];
    const float* u_V    = (const float*)d_in[5];
    const float* t_V    = (const float*)d_in[6];
    const float* b_V    = (const float*)d_in[7];
    float* out = (float*)d_out;
    float* ws  = (float*)d_ws;

    int P = in_sizes[0];  // 2,000,000

    hipLaunchKernelGGL(zero_ws_kernel, dim3(1), dim3(256), 0, stream, ws);

    int nvec = (P + 3) / 4;              // float4 lanes
    int blocks = (nvec + 255) / 256;     // ~1954 blocks
    hipLaunchKernelGGL(scan_accum_kernel, dim3(blocks), dim3(256), 0, stream,
                       x, w_bias, u_V, t_V, b_V, ws, P);

    hipLaunchKernelGGL(finalize_kernel, dim3(1), dim3(64), 0, stream,
                       ws, w0, delta, out);
}